// Round 8
// baseline (363.531 us; speedup 1.0000x reference)
//
#include <hip/hip_runtime.h>
#include <hip/hip_bf16.h>
#include <math.h>

// Problem constants
#define BB 8
#define SS 512
#define DD 768
#define LL 200

typedef __attribute__((ext_vector_type(8))) short bf16x8;
typedef __attribute__((ext_vector_type(4))) float f32x4;

__device__ inline short f2bf(float f) {
    unsigned u = __builtin_bit_cast(unsigned, f);
    unsigned r = (u + 0x7FFFu + ((u >> 16) & 1u)) >> 16;
    return (short)r;
}

#define LDP2 72    // GEMM LDS row pitch (144 B = 9*16B odd)
#define WP 168     // conv W pitch (336 B = 21*16B odd)
#define TP 24      // winT pitch (48 B)
#define WTR 217
#define WROWS 208
#define APAD 256   // K-pitch for K=200 bf16 operands
#define NBLK 96    // chain/tail grid size (<< 256 CUs -> co-resident)
#define BIGN (1 << 30)

// ---------------------------------------------------------------------------
// software grid barrier: device-scope atomic + device fences (cross-XCD safe)
// ---------------------------------------------------------------------------
__device__ inline void gbar(int* cnt, int target)
{
    __syncthreads();
    if (threadIdx.x == 0) {
        __threadfence();                       // release: writeback L2
        atomicAdd(cnt, 1);
        while (atomicAdd(cnt, 0) < target) __builtin_amdgcn_s_sleep(2);
        __threadfence();                       // acquire: invalidate stale
    }
    __syncthreads();
}

// ---------------------------------------------------------------------------
// device GEMM (verified BK=64 structure): C[M,N] = epi(A_bf16 @ B + bias)
//  virtual tile id blk -> (bm,bn); returns immediately if blk >= tiles
// ---------------------------------------------------------------------------
template<int EPI, bool TB>
__device__ void dev_gemm(short* As, short* Bs,
    const short* __restrict__ A, int lda,
    const void* __restrict__ Bv, int ldb,
    const float* __restrict__ bias,
    const void* __restrict__ Bv2, const float* __restrict__ bias2, int nsplit,
    float* __restrict__ Cf, int ldc,
    short* __restrict__ Cb, int ldcb,
    int M, int N, int K, int blk)
{
    const int nTiles = (N + 63) >> 6;
    const int mTiles = (M + 63) >> 6;
    if (blk >= nTiles * mTiles) return;
    const int bm = (blk / nTiles) * 64;
    const int bn = (blk % nTiles) * 64;
    int bnb = bn;
    if (!TB && bn >= nsplit) { Bv = Bv2; bias = bias2; bnb = bn - nsplit; }
    const int tid = threadIdx.x;
    const int w = tid >> 6, lane = tid & 63, g = lane >> 4, ln = lane & 15;
    const int Kp = (K + 63) & ~63;
    const int nt = Kp >> 6;

    const int ar = tid >> 2, ac = tid & 3;
    const int bkk = tid >> 2, bc = tid & 3;

    f32x4 acc[4];
    #pragma unroll
    for (int i = 0; i < 4; ++i) acc[i] = (f32x4){0.f, 0.f, 0.f, 0.f};

    bf16x8 aR0 = {0,0,0,0,0,0,0,0}, aR1 = {0,0,0,0,0,0,0,0};
    bf16x8 bR0 = {0,0,0,0,0,0,0,0}, bR1 = {0,0,0,0,0,0,0,0};
    float  bF[16];
    #pragma unroll
    for (int j = 0; j < 16; ++j) bF[j] = 0.f;

    const int gmS = bm + ar;
    const bool aOk = (gmS < M);

    auto fetchA = [&](int k0) {
        if (aOk) {
            const short* p = A + (size_t)gmS * lda + k0 + ac * 16;
            aR0 = *(const bf16x8*)p;
            aR1 = *(const bf16x8*)(p + 8);
        }
    };
    auto fetchB = [&](int k0) {
        if (TB) {
            const short* Bt = (const short*)Bv;
            int gn = bn + ar;
            if (gn < N) {
                const short* p = Bt + (size_t)gn * ldb + k0 + ac * 16;
                bR0 = *(const bf16x8*)p;
                bR1 = *(const bf16x8*)(p + 8);
            }
        } else {
            const float* Bp = (const float*)Bv;
            int gk = k0 + bkk;
            int n0 = bnb + bc * 16;
            int gn0 = bn + bc * 16;
            if (gk < K) {
                const float* p = Bp + (size_t)gk * ldb + n0;
                if (gn0 + 16 <= N) {
                    #pragma unroll
                    for (int q = 0; q < 4; ++q) {
                        float4 x = *(const float4*)(p + q * 4);
                        bF[q*4+0]=x.x; bF[q*4+1]=x.y; bF[q*4+2]=x.z; bF[q*4+3]=x.w;
                    }
                } else {
                    #pragma unroll
                    for (int j = 0; j < 16; ++j) bF[j] = (gn0 + j < N) ? p[j] : 0.f;
                }
            } else {
                #pragma unroll
                for (int j = 0; j < 16; ++j) bF[j] = 0.f;
            }
        }
    };

    fetchA(0);
    fetchB(0);

    for (int t = 0; t < nt; ++t) {
        {
            short* pa = As + ar * LDP2 + ac * 16;
            *(bf16x8*)pa = aR0;
            *(bf16x8*)(pa + 8) = aR1;
        }
        if (TB) {
            short* pb = Bs + ar * LDP2 + ac * 16;
            *(bf16x8*)pb = bR0;
            *(bf16x8*)(pb + 8) = bR1;
        } else {
            #pragma unroll
            for (int j = 0; j < 16; ++j)
                Bs[(bc * 16 + j) * LDP2 + bkk] = f2bf(bF[j]);
        }
        __syncthreads();

        if (t + 1 < nt) {
            int k0 = (t + 1) << 6;
            fetchA(k0);
            fetchB(k0);
        }

        #pragma unroll
        for (int ks = 0; ks < 2; ++ks) {
            bf16x8 a = *(const bf16x8*)(As + (w * 16 + ln) * LDP2 + ks * 32 + g * 8);
            #pragma unroll
            for (int nb = 0; nb < 4; ++nb) {
                bf16x8 b = *(const bf16x8*)(Bs + (nb * 16 + ln) * LDP2 + ks * 32 + g * 8);
                acc[nb] = __builtin_amdgcn_mfma_f32_16x16x32_bf16(a, b, acc[nb], 0, 0, 0);
            }
        }
        __syncthreads();
    }

    #pragma unroll
    for (int nb = 0; nb < 4; ++nb) {
        int gn = bn + nb * 16 + ln;
        float bv = (bias && gn < N) ? bias[bnb + nb * 16 + ln] : 0.f;
        #pragma unroll
        for (int r = 0; r < 4; ++r) {
            int gm = bm + w * 16 + g * 4 + r;
            if (gm < M && gn < N) {
                float v = acc[nb][r] + bv;
                if (EPI == 1) v = (v >= 0.f) ? v : 0.2f * v;
                else if (EPI == 2) v = 1.f / (1.f + expf(-v));
                if (Cf) Cf[(size_t)gm * ldc + gn] = v;
                if (Cb) Cb[(size_t)gm * ldcb + gn] = f2bf(v);
            }
        }
    }
}

// ---------------------------------------------------------------------------
// chain_k: the ENTIRE label-side pipeline + doc l1norm, one launch, 96 blocks
// ---------------------------------------------------------------------------
__global__ __launch_bounds__(256) void chain_k(
    const float* __restrict__ label_emb, const float* __restrict__ label_adj,
    const float* __restrict__ w_gcn3, const float* __restrict__ w_gcn5,
    const float* __restrict__ w_ll1, const float* __restrict__ b_ll1,
    const float* __restrict__ w_ll2, const float* __restrict__ b_ll2,
    const float* __restrict__ w_lin, const float* __restrict__ b_lin,
    const float* __restrict__ cw, const float* __restrict__ cb,
    const float* __restrict__ doc,
    short* wkg, short* adj_bf, short* E2_bf, float* le_f, short* le_cat_bf,
    short* qk_bf, float* Amat, float* dvec, short* Anorm_bf, short* G_bf,
    float* le_out_f, short* le_out_bf, float* denom, short* doc_nb,
    int* cnt)
{
    __shared__ __align__(16) short As[64 * LDP2];
    __shared__ __align__(16) short Bs[64 * LDP2];
    __shared__ float cred[4];
    __shared__ float dred[4][64];

    const int blk = blockIdx.x;
    const int tid = threadIdx.x;

    // S0: prep conv weights (kappa order + bias tap) and padded adjacency
    for (int idx = blk * 256 + tid; idx < WROWS * WP + LL * APAD; idx += NBLK * 256) {
        if (idx < WROWS * WP) {
            int o = idx / WP, kk = idx % WP;
            int kj = kk >> 4, ki = kk & 15;
            float v = 0.f;
            if (o < LL && kj < 9) {
                if (ki < 9) v = cw[o * 81 + ki * 9 + kj];
                else if (ki == 9 && kj == 0) v = cb[o];
            }
            wkg[idx] = f2bf(v);
        } else {
            int j2 = idx - WROWS * WP;
            int r = j2 / APAD, c = j2 % APAD;
            adj_bf[j2] = f2bf(c < LL ? label_adj[r * LL + c] : 0.f);
        }
    }
    gbar(cnt, NBLK * 1);

    // S1: E2 = adj @ emb   [200,768] K=200
    dev_gemm<0, false>(As, Bs, adj_bf, APAD, label_emb, DD, nullptr,
                       nullptr, nullptr, BIGN, nullptr, 0, E2_bf, DD, LL, DD, LL, blk);
    gbar(cnt, NBLK * 2);

    // S2: le = leaky(E2 @ W3) -> f32 + bf16 (le_cat[:, :768])
    dev_gemm<1, false>(As, Bs, E2_bf, DD, w_gcn3, DD, nullptr,
                       nullptr, nullptr, BIGN, le_f, DD, le_cat_bf, 1536, LL, DD, DD, blk);
    gbar(cnt, NBLK * 3);

    // S3: [q|k] = le @ [w_ll1|w_ll2] + [b1|b2]  (N=1536, 96 tiles)
    dev_gemm<0, false>(As, Bs, le_cat_bf, 1536, w_ll1, DD, b_ll1,
                       w_ll2, b_ll2, DD, nullptr, 0, qk_bf, 1536, LL, 2 * DD, DD, blk);
    gbar(cnt, NBLK * 4);

    // S4: A = sigmoid(q @ k^T)   [200,200]
    dev_gemm<2, true>(As, Bs, qk_bf, 1536, qk_bf + DD, 1536, nullptr,
                      nullptr, nullptr, BIGN, Amat, LL, nullptr, 0, LL, LL, DD, blk);
    gbar(cnt, NBLK * 5);

    // S5a: dvec[j] = rsqrt(colsum_j(A))
    for (int j = blk; j < LL; j += NBLK) {
        float s = (tid < LL) ? Amat[tid * LL + j] : 0.f;
        #pragma unroll
        for (int off = 32; off > 0; off >>= 1) s += __shfl_down(s, off, 64);
        if ((tid & 63) == 0) cred[tid >> 6] = s;
        __syncthreads();
        if (tid == 0) {
            float t = cred[0] + cred[1] + cred[2] + cred[3];
            dvec[j] = (t > 0.f) ? (1.f / sqrtf(t)) : 0.f;
        }
        __syncthreads();
    }
    gbar(cnt, NBLK * 6);

    // S5b: Anorm[i][j] = bf16(A[j,i] * d[i] * d[j]), padded APAD
    for (int idx = blk * 256 + tid; idx < LL * APAD; idx += NBLK * 256) {
        int i = idx / APAD, j = idx % APAD;
        float v = (j < LL) ? Amat[j * LL + i] * dvec[i] * dvec[j] : 0.f;
        Anorm_bf[idx] = f2bf(v);
    }
    gbar(cnt, NBLK * 7);

    // S6: G = Anorm @ le   K=200
    dev_gemm<0, false>(As, Bs, Anorm_bf, APAD, le_f, DD, nullptr,
                       nullptr, nullptr, BIGN, nullptr, 0, G_bf, DD, LL, DD, LL, blk);
    gbar(cnt, NBLK * 8);

    // S7: d_le = leaky(G @ W5) -> le_cat[:, 768:]
    dev_gemm<1, false>(As, Bs, G_bf, DD, w_gcn5, DD, nullptr,
                       nullptr, nullptr, BIGN, nullptr, 0, le_cat_bf + DD, 1536, LL, DD, DD, blk);
    gbar(cnt, NBLK * 9);

    // S8: le_out = le_cat @ w_lin + b_lin   K=1536
    dev_gemm<0, false>(As, Bs, le_cat_bf, 1536, w_lin, DD, b_lin,
                       nullptr, nullptr, BIGN, le_out_f, DD, nullptr, 0, LL, DD, 2 * DD, blk);
    gbar(cnt, NBLK * 10);

    // S9: l1-normalize le_out over L (block = 8 cols x 32 lanes)
    {
        int c = tid >> 5, r = tid & 31;
        int col = blk * 8 + c;                 // 96*8 = 768
        float s = 0.f;
        for (int l = r; l < LL; l += 32) s += fabsf(le_out_f[l * DD + col]);
        #pragma unroll
        for (int off = 16; off > 0; off >>= 1) s += __shfl_xor(s, off, 64);
        float inv = 1.f / fmaxf(s, 1e-12f);
        for (int l = r; l < LL; l += 32)
            le_out_bf[l * DD + col] = f2bf(le_out_f[l * DD + col] * inv);
    }

    // S10: doc l1norm (self-contained per block: b = blk/12, d-chunk = blk%12)
    {
        int bq = blk / 12, dc = blk % 12;
        int dx = tid & 63, sy = tid >> 6;
        int d = dc * 64 + dx;
        const float* pp = doc + (size_t)bq * SS * DD + d;
        float s = 0.f;
        for (int t = sy; t < SS; t += 4) s += fabsf(pp[(size_t)t * DD]);
        dred[sy][dx] = s;
        __syncthreads();
        float dn = fmaxf(dred[0][dx] + dred[1][dx] + dred[2][dx] + dred[3][dx], 1e-12f);
        if (sy == 0) denom[bq * DD + d] = dn;
        float inv = 1.f / dn;
        short* qq = doc_nb + (size_t)bq * SS * DD + d;
        for (int t = sy; t < SS; t += 4) qq[(size_t)t * DD] = f2bf(pp[(size_t)t * DD] * inv);
    }
}

// ---------------------------------------------------------------------------
// wla = doc_n @ le_out^T   [4096,200] K=768  (256 tiles, own launch)
// ---------------------------------------------------------------------------
__global__ __launch_bounds__(256) void wla_k(const short* __restrict__ doc_nb,
                                             const short* __restrict__ le_out_bf,
                                             float* __restrict__ wla)
{
    __shared__ __align__(16) short As[64 * LDP2];
    __shared__ __align__(16) short Bs[64 * LDP2];
    dev_gemm<0, true>(As, Bs, doc_nb, DD, le_out_bf, DD, nullptr,
                      nullptr, nullptr, BIGN, wla, LL, nullptr, 0, BB * SS, LL, DD,
                      blockIdx.x);
}

// ---------------------------------------------------------------------------
// conv kernel — UNCHANGED from round 7 (verified, 62 us)
// ---------------------------------------------------------------------------
__global__ __launch_bounds__(512, 1) void conv_max_k(
    const float* __restrict__ wla,
    const short* __restrict__ wkg,
    float* __restrict__ gate)
{
    extern __shared__ short smem[];
    short* Wk   = smem;
    short* winT = Wk + WROWS * WP;
    short* wbf  = winT + 4 * WTR * TP;
    __shared__ float wredf[8];

    const int blk = blockIdx.x;
    const int b = blk >> 7;
    const int s0 = (blk & 127) << 2;
    const int tid = threadIdx.x;

    {
        const int4* src = (const int4*)wkg;
        int4* dst = (int4*)Wk;
        for (int i = tid; i < WROWS * WP / 8; i += 512) dst[i] = src[i];
    }
    for (int idx = tid; idx < 12 * 216; idx += 512) {
        int r = idx / 216, c = idx % 216;
        int sr = s0 - 4 + r, col = c - 4;
        float v = 0.f;
        if (sr >= 0 && sr < SS && col >= 0 && col < LL)
            v = wla[((size_t)b * SS + sr) * LL + col];
        wbf[idx] = f2bf(v);
    }
    __syncthreads();
    for (int idx = tid; idx < 4 * WTR; idx += 512) {
        int p = idx / WTR, r = idx % WTR;
        short vals[16];
        #pragma unroll
        for (int i = 0; i < 9; ++i) vals[i] = (r < 216) ? wbf[(p + i) * 216 + r] : (short)0;
        vals[9] = (short)0x3F80;
        #pragma unroll
        for (int i = 10; i < 16; ++i) vals[i] = 0;
        short* dstp = winT + (p * WTR + r) * TP;
        *(bf16x8*)dstp = *(const bf16x8*)vals;
        *(bf16x8*)(dstp + 8) = *(const bf16x8*)(vals + 8);
    }
    __syncthreads();

    const int w = tid >> 6;
    const int p = w >> 1;
    const int h = w & 1;
    const int lane = tid & 63;
    const int g = lane >> 4;
    const int ln = lane & 15;
    const short* WT = winT + p * WTR * TP;

    bf16x8 Af[7][5];
    #pragma unroll
    for (int s = 0; s < 7; ++s) {
        int st = h * 7 + s;
        if (st > 12) st = 12;
        #pragma unroll
        for (int j = 0; j < 5; ++j)
            Af[s][j] = *(const bf16x8*)(Wk + (st * 16 + ln) * WP + j * 32 + g * 8);
    }

    float lm = -INFINITY;

    auto loadB = [&](int nt, bf16x8 (&Bf)[5]) {
        #pragma unroll
        for (int j = 0; j < 5; ++j)
            Bf[j] = *(const bf16x8*)(WT + (nt * 16 + ln + 2 * j + (g >> 1)) * TP + (g & 1) * 8);
    };
    auto compute = [&](int nt, const bf16x8 (&Bf)[5]) {
        #pragma unroll
        for (int s = 0; s < 7; ++s) {
            if (h == 0 || s < 6) {
                int st = h * 7 + s;
                f32x4 acc = {0.f, 0.f, 0.f, 0.f};
                #pragma unroll
                for (int j = 0; j < 5; ++j)
                    acc = __builtin_amdgcn_mfma_f32_16x16x32_bf16(Af[s][j], Bf[j], acc, 0, 0, 0);
                float t = fmaxf(fmaxf(acc[0], acc[1]), fmaxf(acc[2], acc[3]));
                bool ok = (st < 12 || g < 2) && (nt < 12 || ln < 8);
                lm = ok ? fmaxf(lm, t) : lm;
            }
        }
    };

    bf16x8 B0[5], B1[5];
    loadB(0, B0);
    for (int nt = 0; nt < 12; nt += 2) {
        loadB(nt + 1, B1);
        compute(nt, B0);
        loadB(nt + 2, B0);
        compute(nt + 1, B1);
    }
    compute(12, B0);

    #pragma unroll
    for (int off = 32; off > 0; off >>= 1)
        lm = fmaxf(lm, __shfl_xor(lm, off, 64));
    if (lane == 0) wredf[w] = lm;
    __syncthreads();
    if (tid < 4)
        gate[((size_t)b << 9) + s0 + tid] = tanhf(fmaxf(wredf[2 * tid], wredf[2 * tid + 1]));
}

// ---------------------------------------------------------------------------
// tail_k: henc partials -> barrier -> final linear+sigmoid -> barrier -> loss
// ---------------------------------------------------------------------------
__global__ __launch_bounds__(256) void tail_k(
    const float* __restrict__ doc, const float* __restrict__ gate,
    const float* __restrict__ denom, const float* __restrict__ W,
    const float* __restrict__ bias, const float* __restrict__ labels,
    float* hpart, float* out, int* cnt)
{
    __shared__ float red[4][64];
    __shared__ float hb[DD];
    __shared__ float ws4[4];
    const int blk = blockIdx.x;
    const int tid = threadIdx.x;

    // T0: hpart over 768 units (12 dchunk x 8 schunk x 8 b)
    for (int u = blk; u < 768; u += NBLK) {
        int dc = u % 12, sc = (u / 12) % 8, b = u / 96;
        int dx = tid & 63, sy = tid >> 6;
        int d = dc * 64 + dx;
        float s = 0.f;
        for (int t = sy; t < 64; t += 4) {
            int srow = sc * 64 + t;
            s = fmaf(doc[((size_t)b * SS + srow) * DD + d], gate[b * SS + srow], s);
        }
        red[sy][dx] = s;
        __syncthreads();
        if (sy == 0)
            hpart[((size_t)b * 8 + sc) * DD + d] = red[0][dx] + red[1][dx] + red[2][dx] + red[3][dx];
        __syncthreads();
    }
    gbar(cnt, NBLK * 1);

    // T1: final linear + sigmoid (blocks 0..7)
    if (blk < BB) {
        int b = blk;
        for (int idx = tid; idx < DD; idx += 256) {
            float s = 0.f;
            #pragma unroll
            for (int sc = 0; sc < 8; ++sc) s += hpart[((size_t)b * 8 + sc) * DD + idx];
            hb[idx] = s / denom[b * DD + idx];
        }
        __syncthreads();
        int l = tid;
        if (l < LL) {
            float acc = bias[l];
            for (int d = 0; d < DD; ++d) acc = fmaf(hb[d], W[d * LL + l], acc);
            out[b * LL + l] = 1.f / (1.f + expf(-acc));
        }
    }
    gbar(cnt, NBLK * 2);

    // T2: loss (block 0)
    if (blk == 0) {
        float s = 0.f;
        for (int i = tid; i < BB * LL; i += 256) {
            float p = out[i];
            p = fminf(fmaxf(p, 1e-7f), 1.f - 1e-7f);
            float y = labels[i];
            s += y * logf(p) + (1.f - y) * logf(1.f - p);
        }
        #pragma unroll
        for (int off = 32; off > 0; off >>= 1) s += __shfl_down(s, off, 64);
        if ((tid & 63) == 0) ws4[tid >> 6] = s;
        __syncthreads();
        if (tid == 0)
            out[BB * LL] = -(ws4[0] + ws4[1] + ws4[2] + ws4[3]) / (float)(BB * LL);
    }
}

// ---------------------------------------------------------------------------
extern "C" void kernel_launch(void* const* d_in, const int* in_sizes, int n_in,
                              void* d_out, int out_size, void* d_ws, size_t ws_size,
                              hipStream_t stream)
{
    const float* doc_emb   = (const float*)d_in[0];
    const float* labels    = (const float*)d_in[1];
    const float* label_emb = (const float*)d_in[2];
    const float* label_adj = (const float*)d_in[3];
    const float* w_gcn3    = (const float*)d_in[4];
    const float* w_gcn5    = (const float*)d_in[5];
    const float* w_ll1     = (const float*)d_in[6];
    const float* b_ll1     = (const float*)d_in[7];
    const float* w_ll2     = (const float*)d_in[8];
    const float* b_ll2     = (const float*)d_in[9];
    const float* w_lin     = (const float*)d_in[10];
    const float* b_lin     = (const float*)d_in[11];
    const float* conv_w    = (const float*)d_in[12];
    const float* conv_b    = (const float*)d_in[13];
    const float* w_lin1    = (const float*)d_in[14];
    const float* b_lin1    = (const float*)d_in[15];

    float* out = (float*)d_out;   // [B*L] + [1]

    char* p = (char*)d_ws;
    auto alloc = [&](size_t bytes) { void* r = p; p += (bytes + 15) & ~(size_t)15; return r; };
    int*   cnt       = (int*)alloc(16);                 // [cnt0, cnt1]
    short* wkg       = (short*)alloc(WROWS * WP * 2);
    short* adj_bf    = (short*)alloc(200 * APAD * 2);
    short* E2_bf     = (short*)alloc(200 * 768 * 2);
    float* le_f      = (float*)alloc(200 * 768 * 4);
    short* le_cat_bf = (short*)alloc(200 * 1536 * 2);
    short* qk_bf     = (short*)alloc(200 * 1536 * 2);
    float* Amat      = (float*)alloc(200 * 200 * 4);
    float* dvec      = (float*)alloc(256 * 4);
    short* Anorm_bf  = (short*)alloc(200 * APAD * 2);
    short* G_bf      = (short*)alloc(200 * 768 * 2);
    float* le_out_f  = (float*)alloc(200 * 768 * 4);
    short* le_out_bf = (short*)alloc(200 * 768 * 2);
    float* denom     = (float*)alloc(BB * DD * 4);
    short* doc_nb    = (short*)alloc((size_t)BB * SS * DD * 2);
    float* wla       = (float*)alloc((size_t)BB * SS * LL * 4);
    float* gatev     = (float*)alloc(BB * SS * 4);
    float* hpart     = (float*)alloc(BB * 8 * DD * 4);

    // zero the barrier counters (captured as a memset node; runs every replay)
    hipMemsetAsync(cnt, 0, 16, stream);

    // 1. whole label-side chain + doc l1norm (one launch, 10 grid barriers)
    chain_k<<<NBLK, 256, 0, stream>>>(
        label_emb, label_adj, w_gcn3, w_gcn5, w_ll1, b_ll1, w_ll2, b_ll2,
        w_lin, b_lin, conv_w, conv_b, doc_emb,
        wkg, adj_bf, E2_bf, le_f, le_cat_bf, qk_bf, Amat, dvec, Anorm_bf,
        G_bf, le_out_f, le_out_bf, denom, doc_nb, cnt);

    // 2. wla = doc_n @ le_out^T
    wla_k<<<256, 256, 0, stream>>>(doc_nb, le_out_bf, wla);

    // 3. conv + max + tanh
    (void)hipFuncSetAttribute((const void*)conv_max_k,
                              hipFuncAttributeMaxDynamicSharedMemorySize, 116736);
    conv_max_k<<<1024, 512, 116736, stream>>>(wla, wkg, gatev);

    // 4. henc + final + loss (one launch, 2 grid barriers)
    tail_k<<<NBLK, 256, 0, stream>>>(doc_emb, gatev, denom, w_lin1, b_lin1,
                                     labels, hpart, out, cnt + 1);
}